// Round 3
// baseline (12.552 us; speedup 1.0000x reference)
//
#include <hip/hip_runtime.h>
#include <hip/hip_bf16.h>

// out[b, p, d] = mean_{j=0..7} emb[x[b, p*8 + j], d]
// B=16, T=16384, MAX_PATCH=8, D=128, VOCAB=256.
// Patches = 32768, out float4s = 1,048,576.
//
// R2: overlap table staging with compute.
//  - Stage the 128 KB fp32 table into LDS via global_load_lds (async DMA,
//    wave-uniform base + lane*16 linear layout — the required pattern).
//  - While the DMA is in flight, compute iteration 0 gathering from GLOBAL
//    (L2-warm: staging pulls the same lines).
//  - One __syncthreads (drains vmcnt -> staging done), then iterations 1-3
//    gather from LDS.

#define NPATCH  32768
#define TPB     1024
#define NBLK    256
#define GROUPS_PER_BLOCK (TPB / 32)            // 32
#define NGROUPS (NBLK * GROUPS_PER_BLOCK)      // 8192
#define ITERS   (NPATCH / NGROUPS)             // 4

__global__ __launch_bounds__(TPB, 1) void blt_patch_mean_lds(
    const int4* __restrict__ x4,      // [NPATCH*2] int4 view of [B*T] indices
    const float4* __restrict__ emb4,  // [256*32] float4 view of [256][128] f32
    float4* __restrict__ out4)        // [NPATCH*32] float4 view of output
{
    __shared__ float4 tbl[8192];      // 128 KB

    // --- async stage: thread k copies emb4[i*TPB+k] -> tbl[i*TPB+k], 16 B ---
    {
        const float4* gsrc = emb4 + threadIdx.x;
        float4*       ldst = tbl  + threadIdx.x;
        #pragma unroll
        for (int i = 0; i < 8; ++i) {
            __builtin_amdgcn_global_load_lds(
                (const __attribute__((address_space(1))) unsigned int*)(gsrc + i * TPB),
                (__attribute__((address_space(3))) unsigned int*)(ldst + i * TPB),
                16, 0, 0);
        }
    }

    const int group0 = (int)blockIdx.x * GROUPS_PER_BLOCK + ((int)threadIdx.x >> 5);
    const int col    = threadIdx.x & 31;
    const float s    = 0.125f;        // 1/MAX_PATCH

    // --- iteration 0: gather from GLOBAL while staging DMA is in flight ---
    {
        const int p = group0;
        int4 i0 = x4[p * 2];
        int4 i1 = x4[p * 2 + 1];
        float4 acc = make_float4(0.f, 0.f, 0.f, 0.f);
        #define ACCUMG(r) { float4 v = emb4[(r) * 32 + col];                   \
                            acc.x += v.x; acc.y += v.y; acc.z += v.z; acc.w += v.w; }
        ACCUMG(i0.x); ACCUMG(i0.y); ACCUMG(i0.z); ACCUMG(i0.w);
        ACCUMG(i1.x); ACCUMG(i1.y); ACCUMG(i1.z); ACCUMG(i1.w);
        #undef ACCUMG
        acc.x *= s; acc.y *= s; acc.z *= s; acc.w *= s;
        out4[p * 32 + col] = acc;
    }

    __syncthreads();   // drains vmcnt(0): staging DMA complete, LDS valid

    // --- iterations 1..3: gather from LDS ---
    #pragma unroll
    for (int it = 1; it < ITERS; ++it) {
        const int p = group0 + it * NGROUPS;
        int4 i0 = x4[p * 2];
        int4 i1 = x4[p * 2 + 1];
        float4 acc = make_float4(0.f, 0.f, 0.f, 0.f);
        #define ACCUM(r) { float4 v = tbl[(r) * 32 + col];                     \
                           acc.x += v.x; acc.y += v.y; acc.z += v.z; acc.w += v.w; }
        ACCUM(i0.x); ACCUM(i0.y); ACCUM(i0.z); ACCUM(i0.w);
        ACCUM(i1.x); ACCUM(i1.y); ACCUM(i1.z); ACCUM(i1.w);
        #undef ACCUM
        acc.x *= s; acc.y *= s; acc.z *= s; acc.w *= s;
        out4[p * 32 + col] = acc;
    }
}

extern "C" void kernel_launch(void* const* d_in, const int* in_sizes, int n_in,
                              void* d_out, int out_size, void* d_ws, size_t ws_size,
                              hipStream_t stream)
{
    const int4*   x4   = (const int4*)d_in[0];    // [16*16384] int32 -> int4
    const float4* emb4 = (const float4*)d_in[1];  // [256*128] f32 -> float4
    float4*       out4 = (float4*)d_out;

    blt_patch_mean_lds<<<NBLK, TPB, 0, stream>>>(x4, emb4, out4);
}

// Round 5
// 11.804 us; speedup vs baseline: 1.0633x; 1.0633x over previous
//
#include <hip/hip_runtime.h>
#include <hip/hip_bf16.h>

// out[b, p, d] = mean_{j=0..7} emb[x[b, p*8 + j], d]
// B=16, T=16384, MAX_PATCH=8, D=128, VOCAB=256.
// Patches = 32768, out float4s = 1,048,576.
//
// R4 = R3 with the nontemporal-store type fixed (native ext_vector_type(4)
// instead of HIP_vector_type float4, which the builtin rejects).
//  - 256 blocks (1/CU) x 1024 threads.
//  - Stage full 128 KB fp32 table via global_load_lds DMA (fire-and-forget).
//  - While DMA is in flight, prefetch ALL 4 iterations' indices into regs.
//  - One __syncthreads (drains vmcnt(0) -> LDS valid).
//  - 4 iterations of pure-LDS gather + nontemporal stores (output is
//    write-once, never re-read -> don't evict the L2-resident table).

#define NPATCH  32768
#define TPB     1024
#define NBLK    256
#define GPB     (TPB / 32)           // 32 half-wave groups per block
#define NGROUPS (NBLK * GPB)         // 8192
#define ITERS   (NPATCH / NGROUPS)   // 4

typedef float nfloat4 __attribute__((ext_vector_type(4)));

__global__ __launch_bounds__(TPB, 1) void blt_patch_mean_r4(
    const int4* __restrict__ x4,      // [NPATCH*2] int4 view of [B*T] indices
    const float4* __restrict__ emb4,  // [256*32] float4 view of [256][128] f32
    float4* __restrict__ out4)        // [NPATCH*32] float4 view of output
{
    __shared__ float4 tbl[8192];      // 128 KB

    // --- async DMA stage: wave-uniform base + lane*16, linear layout ---
    {
        const float4* gsrc = emb4 + threadIdx.x;
        float4*       ldst = tbl  + threadIdx.x;
        #pragma unroll
        for (int i = 0; i < 8; ++i) {
            __builtin_amdgcn_global_load_lds(
                (const __attribute__((address_space(1))) unsigned int*)(gsrc + i * TPB),
                (__attribute__((address_space(3))) unsigned int*)(ldst + i * TPB),
                16, 0, 0);
        }
    }

    const int group0 = (int)blockIdx.x * GPB + ((int)threadIdx.x >> 5);
    const int col    = threadIdx.x & 31;
    const float s    = 0.125f;        // 1/MAX_PATCH

    // --- prefetch all indices while DMA is in flight (broadcast loads) ---
    int4 ia[ITERS], ib[ITERS];
    #pragma unroll
    for (int it = 0; it < ITERS; ++it) {
        const int p = group0 + it * NGROUPS;
        ia[it] = x4[p * 2];
        ib[it] = x4[p * 2 + 1];
    }

    __syncthreads();   // drains vmcnt(0): staging DMA complete, LDS valid

    // --- 4 iterations of pure-LDS gather ---
    #pragma unroll
    for (int it = 0; it < ITERS; ++it) {
        const int p = group0 + it * NGROUPS;
        float4 acc = make_float4(0.f, 0.f, 0.f, 0.f);
        #define ACCUM(r) { float4 v = tbl[(r) * 32 + col];                     \
                           acc.x += v.x; acc.y += v.y; acc.z += v.z; acc.w += v.w; }
        ACCUM(ia[it].x); ACCUM(ia[it].y); ACCUM(ia[it].z); ACCUM(ia[it].w);
        ACCUM(ib[it].x); ACCUM(ib[it].y); ACCUM(ib[it].z); ACCUM(ib[it].w);
        #undef ACCUM
        acc.x *= s; acc.y *= s; acc.z *= s; acc.w *= s;
        nfloat4 v = { acc.x, acc.y, acc.z, acc.w };
        __builtin_nontemporal_store(v, (nfloat4*)&out4[p * 32 + col]);
    }
}

extern "C" void kernel_launch(void* const* d_in, const int* in_sizes, int n_in,
                              void* d_out, int out_size, void* d_ws, size_t ws_size,
                              hipStream_t stream)
{
    const int4*   x4   = (const int4*)d_in[0];    // [16*16384] int32 -> int4
    const float4* emb4 = (const float4*)d_in[1];  // [256*128] f32 -> float4
    float4*       out4 = (float4*)d_out;

    blt_patch_mean_r4<<<NBLK, TPB, 0, stream>>>(x4, emb4, out4);
}